// Round 14
// baseline (4952.135 us; speedup 1.0000x reference)
//
#include <hip/hip_runtime.h>
#include <cmath>

typedef float    f32x4 __attribute__((ext_vector_type(4)));
typedef _Float16 f16x8 __attribute__((ext_vector_type(8)));

#define T_NUM 4096
#define H_DIM 1024
#define I_DIM 4096
#define MAXTILES 40

// ---- meta layout (int32 indices into the meta block) ----
#define M_COUNTS   0      // [3][2][8]
#define M_CURSORS  48     // (unused; kept for layout)
#define M_OFFSETS  96
#define M_NTILES   144    // [3][2]
#define M_TILE_E   152    // [6][40]
#define M_TILE_M   392    // [6][40]
#define M_TOPKI    1024   // int  [3][4096][2]
#define M_TOPKP    25600  // f32  [3][4096][2]
#define M_STOK     50176  // int  [3][8192]
#define M_SPRB     74752  // f32  [3][8192]

__device__ __forceinline__ float wave_sum(float v) {
  v += __shfl_xor(v, 32);
  v += __shfl_xor(v, 16);
  v += __shfl_xor(v, 8);
  v += __shfl_xor(v, 4);
  v += __shfl_xor(v, 2);
  v += __shfl_xor(v, 1);
  return v;
}

// top-2 + softmax, fp32; NO atomics (counts built in route_finalize via LDS)
__device__ __forceinline__ void topk_write(int* meta, int layer, int t, const float* v) {
  int e0 = 0; float v0 = v[0];
  #pragma unroll
  for (int e = 1; e < 8; ++e) { if (v[e] > v0) { v0 = v[e]; e0 = e; } }
  int e1 = 0; float v1 = -3.4e38f;
  #pragma unroll
  for (int e = 0; e < 8; ++e) { if (e != e0 && v[e] > v1) { v1 = v[e]; e1 = e; } }
  float ex = expf(v1 - v0);
  float p0 = 1.f / (1.f + ex);
  float p1 = ex / (1.f + ex);
  meta[M_TOPKI + (layer * T_NUM + t) * 2    ] = e0;
  meta[M_TOPKI + (layer * T_NUM + t) * 2 + 1] = e1;
  ((float*)meta)[M_TOPKP + (layer * T_NUM + t) * 2    ] = p0;
  ((float*)meta)[M_TOPKP + (layer * T_NUM + t) * 2 + 1] = p1;
}

__global__ __launch_bounds__(256) void router_gu(const float* __restrict__ x,
    const float* __restrict__ Rg, const float* __restrict__ Ru, int* __restrict__ meta)
{
  int w = threadIdx.x >> 6, lane = threadIdx.x & 63;
  int t = blockIdx.x * 4 + w;
  const float* xr = x + (size_t)t * H_DIM + lane * 4;
  f32x4 xv[4];
  #pragma unroll
  for (int c = 0; c < 4; ++c) xv[c] = *(const f32x4*)(xr + c * 256);
  float lg[8], lu[8];
  #pragma unroll
  for (int e = 0; e < 8; ++e) {
    const float* rg = Rg + (size_t)e * H_DIM + lane * 4;
    const float* ru = Ru + (size_t)e * H_DIM + lane * 4;
    float sg = 0.f, su = 0.f;
    #pragma unroll
    for (int c = 0; c < 4; ++c) {
      f32x4 a = *(const f32x4*)(rg + c * 256);
      f32x4 b = *(const f32x4*)(ru + c * 256);
      sg += a[0]*xv[c][0] + a[1]*xv[c][1] + a[2]*xv[c][2] + a[3]*xv[c][3];
      su += b[0]*xv[c][0] + b[1]*xv[c][1] + b[2]*xv[c][2] + b[3]*xv[c][3];
    }
    lg[e] = wave_sum(sg);
    lu[e] = wave_sum(su);
  }
  if (lane == 0) {
    topk_write(meta, 0, t, lg);
    topk_write(meta, 1, t, lu);
  }
}

// Single-workgroup routing finalize (LDS atomics; r8-validated).
__global__ __launch_bounds__(256) void route_finalize(int* __restrict__ meta, int l0, int nl) {
  __shared__ int cnt_s[32];
  __shared__ int off_s[32];
  __shared__ int cur_s[32];
  int tid = threadIdx.x;
  if (tid < 32) { cnt_s[tid] = 0; cur_s[tid] = 0; }
  __syncthreads();
  for (int t = tid; t < T_NUM; t += 256) {
    for (int l = l0; l < l0 + nl; ++l) {
      int li = l - l0;
      #pragma unroll
      for (int k = 0; k < 2; ++k) {
        int e = meta[M_TOPKI + (l * T_NUM + t) * 2 + k];
        atomicAdd(&cnt_s[li * 16 + k * 8 + e], 1);
      }
    }
  }
  __syncthreads();
  if (tid == 0) {
    for (int l = l0; l < l0 + nl; ++l) {
      int li = l - l0;
      int off = 0;
      for (int k = 0; k < 2; ++k) {
        int nt = 0;
        for (int e = 0; e < 8; ++e) {
          int s = (l * 2 + k) * 8 + e;
          int c = cnt_s[li * 16 + k * 8 + e];
          meta[M_COUNTS + s] = c;
          meta[M_OFFSETS + s] = off;
          off_s[li * 16 + k * 8 + e] = off;
          for (int m = 0; m < c; m += 128) {
            meta[M_TILE_E + (l * 2 + k) * MAXTILES + nt] = e;
            meta[M_TILE_M + (l * 2 + k) * MAXTILES + nt] = m;
            ++nt;
          }
          off += c;
        }
        meta[M_NTILES + l * 2 + k] = nt;
      }
    }
  }
  __syncthreads();
  for (int t = tid; t < T_NUM; t += 256) {
    for (int l = l0; l < l0 + nl; ++l) {
      int li = l - l0;
      #pragma unroll
      for (int k = 0; k < 2; ++k) {
        int e = meta[M_TOPKI + (l * T_NUM + t) * 2 + k];
        float p = ((float*)meta)[M_TOPKP + (l * T_NUM + t) * 2 + k];
        int si = li * 16 + k * 8 + e;
        int pos = off_s[si] + atomicAdd(&cur_s[si], 1);
        meta[M_STOK + l * 8192 + pos] = t;
        ((float*)meta)[M_SPRB + l * 8192 + pos] = p;
      }
    }
  }
}

// W pre-convert: fp32 [E][N][K] -> tiled f16 hi/lo planes. (Validated r2-r13.)
template<int SPLITS>
__global__ __launch_bounds__(256) void convert_w(const float* __restrict__ W,
    _Float16* __restrict__ Whi, _Float16* __restrict__ Wlo, int NB, int KT)
{
  size_t g = (size_t)blockIdx.x * 256 + threadIdx.x;
  int c   = (int)(g >> 9);
  int rem = (int)(g & 511);
  int fq = rem >> 7, r = rem & 127;
  int e  = c / (NB * KT);
  int nb = (c / KT) % NB;
  int kt = c - (c / KT) * KT;
  int K = KT * 32, N = NB * 128;
  const float* src = W + ((size_t)(e * N + nb * 128 + r)) * K + kt * 32 + fq * 8;
  f32x4 v0 = *(const f32x4*)src;
  f32x4 v1 = *(const f32x4*)(src + 4);
  f16x8 h, l;
  #pragma unroll
  for (int q = 0; q < 8; ++q) {
    float v = (q < 4) ? v0[q] : v1[q - 4];
    _Float16 hv = (_Float16)v;
    h[q] = hv;
    l[q] = (_Float16)(v - (float)hv);
  }
  size_t dst = (size_t)c * 4096 + (size_t)rem * 8;
  *(f16x8*)(Whi + dst) = h;
  if constexpr (SPLITS == 3) *(f16x8*)(Wlo + dst) = l;
}

// A gather+convert (gate/up): x rows -> tile-contiguous hi/lo image. (r6-r13)
__global__ __launch_bounds__(256) void gather_a(const float* __restrict__ X,
    _Float16* __restrict__ Apass, const int* __restrict__ meta, int layer, int kk)
{
  int pass = layer * 2 + kk;
  int tile = blockIdx.x >> 5;            // grid = MAXTILES*32
  int kt   = blockIdx.x & 31;
  if (tile >= meta[M_NTILES + pass]) return;
  int e    = meta[M_TILE_E + pass * MAXTILES + tile];
  int m0   = meta[M_TILE_M + pass * MAXTILES + tile];
  int sidx = pass * 8 + e;
  int cnt  = meta[M_COUNTS + sidx];
  int seg  = meta[M_OFFSETS + sidx];
  const int* stok = meta + M_STOK + layer * 8192 + seg;
  size_t cb = ((size_t)tile * 32 + kt) * 8192;
  #pragma unroll
  for (int j = 0; j < 2; ++j) {
    int idx = threadIdx.x * 2 + j;       // [0,512): fq = idx>>7, row = idx&127
    int fq = idx >> 7, row = idx & 127;
    int m = m0 + row; if (m >= cnt) m = cnt - 1;
    const float* src = X + (size_t)stok[m] * H_DIM + kt * 32 + fq * 8;
    f32x4 v0 = *(const f32x4*)src;
    f32x4 v1 = *(const f32x4*)(src + 4);
    f16x8 h, l;
    #pragma unroll
    for (int q = 0; q < 8; ++q) {
      float v = (q < 4) ? v0[q] : v1[q - 4];
      _Float16 hv = (_Float16)v;
      h[q] = hv;
      l[q] = (_Float16)(v - (float)hv);
    }
    *(f16x8*)(Apass + cb + (size_t)idx * 8) = h;
    *(f16x8*)(Apass + cb + 4096 + (size_t)idx * 8) = l;
  }
}

// A gather+convert (down): inter rows -> tiled f16 image (k-chunk pairs).
__global__ __launch_bounds__(256) void gather_d(const float* __restrict__ G,
    _Float16* __restrict__ Ad, const int* __restrict__ meta, int kk)
{
  int pass = 4 + kk;
  int tile = blockIdx.x >> 7;            // grid = MAXTILES*128
  int kt   = blockIdx.x & 127;
  if (tile >= meta[M_NTILES + pass]) return;
  int e    = meta[M_TILE_E + pass * MAXTILES + tile];
  int m0   = meta[M_TILE_M + pass * MAXTILES + tile];
  int sidx = pass * 8 + e;
  int cnt  = meta[M_COUNTS + sidx];
  int seg  = meta[M_OFFSETS + sidx];
  const int* stok = meta + M_STOK + 2 * 8192 + seg;
  size_t cb = ((size_t)tile * 128 + kt) * 4096;
  #pragma unroll
  for (int j = 0; j < 2; ++j) {
    int idx = threadIdx.x * 2 + j;       // [0,512)
    int fq = idx >> 7, row = idx & 127;
    int m = m0 + row; if (m >= cnt) m = cnt - 1;
    const float* src = G + (size_t)stok[m] * I_DIM + kt * 32 + fq * 8;
    f32x4 v0 = *(const f32x4*)src;
    f32x4 v1 = *(const f32x4*)(src + 4);
    f16x8 h;
    #pragma unroll
    for (int q = 0; q < 8; ++q) h[q] = (_Float16)((q < 4) ? v0[q] : v1[q - 4]);
    *(f16x8*)(Ad + cb + (size_t)idx * 8) = h;
  }
}

// Routed GEMM v13 = r13's no-LDS/no-barrier kernel, with the minwaves bound
// as a template param. r13 measured VGPR=104 at bound (256,2) but only 5
// waves/CU resident — the bound, not the kernel, capped occupancy. Gate/up
// instances use MINW=4 (cap 512/4=128 >= 104 natural: no allocator squeeze,
// 24-reg slack — r11/r12 spill lesson respected). Down (WCH=2, ~168 regs
// natural) stays MINW=2. Zero LDS, zero barriers, per-wave compiler vmcnt on
// 1-step-ahead double-buffered A/W register sets.
template<int MINW, int SPLITS, int ADD, int N, int NB, int STEPS, int SPLITK>
__global__ __launch_bounds__(256, MINW) void moe_gemm13(
    const _Float16* __restrict__ Aimg,
    const _Float16* __restrict__ Whi, const _Float16* __restrict__ Wlo,
    float* __restrict__ Out, float* __restrict__ Scr,
    const int* __restrict__ meta, int layer, int kk)
{
  constexpr int NWG = MAXTILES * NB * SPLITK;
  constexpr int Q8  = NWG / 8;
  constexpr int WCH = (SPLITS == 3) ? 1 : 2;

  int orig = (int)blockIdx.x;
  int logical = (orig & 7) * Q8 + (orig >> 3);
  int kc = 0, rem = logical;
  if constexpr (SPLITK == 2) { kc = logical / (MAXTILES * NB); rem = logical - kc * (MAXTILES * NB); }
  int tx = rem / NB;
  int ny = rem - tx * NB;

  int pass = layer * 2 + kk;
  if (tx >= meta[M_NTILES + pass]) return;
  int e    = meta[M_TILE_E + pass * MAXTILES + tx];
  int m0   = meta[M_TILE_M + pass * MAXTILES + tx];
  int sidx = pass * 8 + e;
  int cnt  = meta[M_COUNTS + sidx];
  int seg  = meta[M_OFFSETS + sidx];
  int n0   = ny * 128;

  int tid = threadIdx.x, lane = tid & 63, w = tid >> 6;
  int wr = w >> 1, wc = w & 1, fr = lane & 15, fq = lane >> 4;

  const int*   stok = meta + M_STOK + layer * 8192 + seg;
  const float* sprb = (const float*)meta + M_SPRB + layer * 8192 + seg;

  // per-lane fragment bases (A image is packed in exact fragment order)
  const _Float16* AtL = Aimg + ((size_t)tx * SPLITK + kc) * STEPS * 8192
                      + (fq * 128 + wr * 64 + fr) * 8;
  size_t wpanel = (size_t)(e * NB + ny) * (STEPS * WCH * SPLITK) * 4096;
  int kb = kc * STEPS * WCH;
  const _Float16* WhL = Whi + wpanel + (size_t)kb * 4096 + (fq * 128 + wc * 64 + fr) * 8;
  const _Float16* WlL = Wlo + wpanel + (size_t)kb * 4096 + (fq * 128 + wc * 64 + fr) * 8;

  auto loadA = [&](int it, f16x8 (&a0)[4], f16x8 (&a1)[4]) {
    const _Float16* s = AtL + (size_t)it * 8192;
    #pragma unroll
    for (int mi = 0; mi < 4; ++mi) a0[mi] = *(const f16x8*)(s + mi * 128);
    #pragma unroll
    for (int mi = 0; mi < 4; ++mi) a1[mi] = *(const f16x8*)(s + 4096 + mi * 128);
  };
  auto loadW = [&](int it, f16x8 (&wh)[WCH][4], f16x8 (&wl)[1][4]) {
    #pragma unroll
    for (int c = 0; c < WCH; ++c) {
      size_t cb = (size_t)(it * WCH + c) * 4096;
      #pragma unroll
      for (int ni = 0; ni < 4; ++ni) wh[c][ni] = *(const f16x8*)(WhL + cb + ni * 128);
    }
    if constexpr (SPLITS == 3) {
      size_t cb = (size_t)it * 4096;
      #pragma unroll
      for (int ni = 0; ni < 4; ++ni) wl[0][ni] = *(const f16x8*)(WlL + cb + ni * 128);
    }
  };

  f32x4 acc[4][4];
  #pragma unroll
  for (int i = 0; i < 4; ++i)
    #pragma unroll
    for (int j = 0; j < 4; ++j) acc[i][j] = f32x4{0.f, 0.f, 0.f, 0.f};

  auto mfma_step = [&](f16x8 (&a0)[4], f16x8 (&a1)[4],
                       f16x8 (&wh)[WCH][4], f16x8 (&wl)[1][4]) {
    __builtin_amdgcn_s_setprio(1);
    if constexpr (SPLITS == 3) {
      #pragma unroll
      for (int mi = 0; mi < 4; ++mi)
        #pragma unroll
        for (int ni = 0; ni < 4; ++ni)
          acc[mi][ni] = __builtin_amdgcn_mfma_f32_16x16x32_f16(a0[mi], wh[0][ni], acc[mi][ni], 0, 0, 0);
      #pragma unroll
      for (int mi = 0; mi < 4; ++mi)
        #pragma unroll
        for (int ni = 0; ni < 4; ++ni)
          acc[mi][ni] = __builtin_amdgcn_mfma_f32_16x16x32_f16(a0[mi], wl[0][ni], acc[mi][ni], 0, 0, 0);
      #pragma unroll
      for (int mi = 0; mi < 4; ++mi)
        #pragma unroll
        for (int ni = 0; ni < 4; ++ni)
          acc[mi][ni] = __builtin_amdgcn_mfma_f32_16x16x32_f16(a1[mi], wh[0][ni], acc[mi][ni], 0, 0, 0);
    } else {
      #pragma unroll
      for (int mi = 0; mi < 4; ++mi)
        #pragma unroll
        for (int ni = 0; ni < 4; ++ni)
          acc[mi][ni] = __builtin_amdgcn_mfma_f32_16x16x32_f16(a0[mi], wh[0][ni], acc[mi][ni], 0, 0, 0);
      #pragma unroll
      for (int mi = 0; mi < 4; ++mi)
        #pragma unroll
        for (int ni = 0; ni < 4; ++ni)
          acc[mi][ni] = __builtin_amdgcn_mfma_f32_16x16x32_f16(a1[mi], wh[1][ni], acc[mi][ni], 0, 0, 0);
    }
    __builtin_amdgcn_s_setprio(0);
  };

  f16x8 a0A[4], a1A[4], a0B[4], a1B[4];
  f16x8 wHA[WCH][4], wLA[1][4], wHB[WCH][4], wLB[1][4];

  loadA(0, a0A, a1A);
  loadW(0, wHA, wLA);
  for (int it = 0; it < STEPS; it += 2) {
    int it1 = (it + 1 < STEPS) ? it + 1 : it;
    int it2 = (it + 2 < STEPS) ? it + 2 : it1;
    loadA(it1, a0B, a1B);
    loadW(it1, wHB, wLB);
    mfma_step(a0A, a1A, wHA, wLA);
    loadA(it2, a0A, a1A);
    loadW(it2, wHA, wLA);
    mfma_step(a0B, a1B, wHB, wLB);
  }

  float* dst = (SPLITK == 2 && kc == 1) ? Scr : Out;
  #pragma unroll
  for (int mi = 0; mi < 4; ++mi) {
    #pragma unroll
    for (int jj = 0; jj < 4; ++jj) {
      int lm = wr * 64 + mi * 16 + fq * 4 + jj;
      int gm = m0 + lm;
      if (gm < cnt) {
        int tok = stok[gm];
        float p = sprb[gm];
        float* orow = dst + (size_t)tok * N + n0 + wc * 64 + fr;
        #pragma unroll
        for (int ni = 0; ni < 4; ++ni) {
          float v = p * acc[mi][ni][jj];
          if constexpr (ADD) orow[ni * 16] += v; else orow[ni * 16] = v;
        }
      }
    }
  }
}

// fused SwiGLU + down-router (atomic-free topk)
__global__ __launch_bounds__(256) void swiglu_router(float* __restrict__ g,
    const float* __restrict__ u, const float* __restrict__ Rd, int* __restrict__ meta)
{
  int t = blockIdx.x, tid = threadIdx.x;
  float part[8];
  #pragma unroll
  for (int e = 0; e < 8; ++e) part[e] = 0.f;
  float* gr = g + (size_t)t * I_DIM;
  const float* ur = u + (size_t)t * I_DIM;
  #pragma unroll
  for (int cc = 0; cc < 4; ++cc) {
    int i = cc * 1024 + tid * 4;
    f32x4 gv = *(const f32x4*)(gr + i);
    f32x4 uv = *(const f32x4*)(ur + i);
    f32x4 iv;
    #pragma unroll
    for (int j = 0; j < 4; ++j) {
      float xx = gv[j];
      iv[j] = (xx / (1.f + expf(-xx))) * uv[j];
    }
    *(f32x4*)(gr + i) = iv;
    #pragma unroll
    for (int e = 0; e < 8; ++e) {
      f32x4 rv = *(const f32x4*)(Rd + (size_t)e * I_DIM + i);
      part[e] += rv[0]*iv[0] + rv[1]*iv[1] + rv[2]*iv[2] + rv[3]*iv[3];
    }
  }
  __shared__ float red[4][8];
  int w = tid >> 6, lane = tid & 63;
  #pragma unroll
  for (int e = 0; e < 8; ++e) {
    float s = wave_sum(part[e]);
    if (lane == 0) red[w][e] = s;
  }
  __syncthreads();
  if (tid == 0) {
    float lg[8];
    #pragma unroll
    for (int e = 0; e < 8; ++e) lg[e] = red[0][e] + red[1][e] + red[2][e] + red[3][e];
    topk_write(meta, 2, t, lg);
  }
}

__global__ __launch_bounds__(256) void combine_kernel(float* __restrict__ out,
                                                      const float* __restrict__ scr)
{
  int i = blockIdx.x * 1024 + threadIdx.x * 4;
  f32x4 a = *(const f32x4*)(out + i);
  f32x4 b = *(const f32x4*)(scr + i);
  #pragma unroll
  for (int j = 0; j < 4; ++j) a[j] += b[j];
  *(f32x4*)(out + i) = a;
}

extern "C" void kernel_launch(void* const* d_in, const int* in_sizes, int n_in,
                              void* d_out, int out_size, void* d_ws, size_t ws_size,
                              hipStream_t stream)
{
  const float* x  = (const float*)d_in[0];
  const float* Rg = (const float*)d_in[1];
  const float* Wg = (const float*)d_in[2];
  const float* Ru = (const float*)d_in[3];
  const float* Wu = (const float*)d_in[4];
  const float* Rd = (const float*)d_in[5];
  const float* Wd = (const float*)d_in[6];
  float* out = (float*)d_out;
  char* ws = (char*)d_ws;

  _Float16* Wth = (_Float16*)ws;                          // 67MB tiled hi plane
  _Float16* Wtl = (_Float16*)(ws + (size_t)67108864);     // 67MB tiled lo plane
  float* g   = (float*)(ws + (size_t)134217728);          // [T, I] fp32 (inter)
  float* u   = (float*)(ws + (size_t)201326592);          // [T, I] fp32; dead after swiglu
  int*  meta = (int*)(ws + (size_t)268435456);            // ~0.4MB
  _Float16* Apass = (_Float16*)(ws + (size_t)269484032);  // 21MB gate/up A image
  _Float16* Ad    = (_Float16*)(ws + (size_t)201326592);  // down A image (in dead u)
  float* dscr     = (float*)(ws + (size_t)269484032);     // down splitK scratch (in dead Apass)

  router_gu<<<dim3(T_NUM / 4), 256, 0, stream>>>(x, Rg, Ru, meta);
  route_finalize<<<dim3(1), 256, 0, stream>>>(meta, 0, 2);

  convert_w<3><<<dim3(16384), 256, 0, stream>>>(Wg, Wth, Wtl, 32, 32);
  gather_a<<<dim3(MAXTILES * 32), 256, 0, stream>>>(x, Apass, meta, 0, 0);
  moe_gemm13<4, 3, 0, I_DIM, 32, 32, 1><<<dim3(MAXTILES * 32), 256, 0, stream>>>(
      Apass, Wth, Wtl, g, g, meta, 0, 0);
  gather_a<<<dim3(MAXTILES * 32), 256, 0, stream>>>(x, Apass, meta, 0, 1);
  moe_gemm13<4, 3, 1, I_DIM, 32, 32, 1><<<dim3(MAXTILES * 32), 256, 0, stream>>>(
      Apass, Wth, Wtl, g, g, meta, 0, 1);

  convert_w<3><<<dim3(16384), 256, 0, stream>>>(Wu, Wth, Wtl, 32, 32);
  gather_a<<<dim3(MAXTILES * 32), 256, 0, stream>>>(x, Apass, meta, 1, 0);
  moe_gemm13<4, 3, 0, I_DIM, 32, 32, 1><<<dim3(MAXTILES * 32), 256, 0, stream>>>(
      Apass, Wth, Wtl, u, u, meta, 1, 0);
  gather_a<<<dim3(MAXTILES * 32), 256, 0, stream>>>(x, Apass, meta, 1, 1);
  moe_gemm13<4, 3, 1, I_DIM, 32, 32, 1><<<dim3(MAXTILES * 32), 256, 0, stream>>>(
      Apass, Wth, Wtl, u, u, meta, 1, 1);

  swiglu_router<<<dim3(T_NUM), 256, 0, stream>>>(g, u, Rd, meta);
  route_finalize<<<dim3(1), 256, 0, stream>>>(meta, 2, 1);

  convert_w<1><<<dim3(16384), 256, 0, stream>>>(Wd, Wth, Wth, 8, 128);
  gather_d<<<dim3(MAXTILES * 128), 256, 0, stream>>>(g, Ad, meta, 0);
  moe_gemm13<2, 1, 0, H_DIM, 8, 32, 2><<<dim3(MAXTILES * 8 * 2), 256, 0, stream>>>(
      Ad, Wth, Wth, out, dscr, meta, 2, 0);
  gather_d<<<dim3(MAXTILES * 128), 256, 0, stream>>>(g, Ad, meta, 1);
  moe_gemm13<2, 1, 1, H_DIM, 8, 32, 2><<<dim3(MAXTILES * 8 * 2), 256, 0, stream>>>(
      Ad, Wth, Wth, out, dscr, meta, 2, 1);
  combine_kernel<<<dim3(T_NUM), 256, 0, stream>>>(out, dscr);
}

// Round 15
// 1052.130 us; speedup vs baseline: 4.7068x; 4.7068x over previous
//
#include <hip/hip_runtime.h>
#include <cmath>

typedef float    f32x4 __attribute__((ext_vector_type(4)));
typedef _Float16 f16x8 __attribute__((ext_vector_type(8)));
typedef _Float16 f16x4 __attribute__((ext_vector_type(4)));

#define T_NUM 4096
#define H_DIM 1024
#define I_DIM 4096
#define MAXTILES 40

// ---- meta layout (int32 indices into the meta block) ----
#define M_COUNTS   0      // [3][2][8]
#define M_CURSORS  48     // (unused; kept for layout)
#define M_OFFSETS  96
#define M_NTILES   144    // [3][2]
#define M_TILE_E   152    // [6][40]
#define M_TILE_M   392    // [6][40]
#define M_TOPKI    1024   // int  [3][4096][2]
#define M_TOPKP    25600  // f32  [3][4096][2]
#define M_STOK     50176  // int  [3][8192]
#define M_SPRB     74752  // f32  [3][8192]

__device__ __forceinline__ float wave_sum(float v) {
  v += __shfl_xor(v, 32);
  v += __shfl_xor(v, 16);
  v += __shfl_xor(v, 8);
  v += __shfl_xor(v, 4);
  v += __shfl_xor(v, 2);
  v += __shfl_xor(v, 1);
  return v;
}

// top-2 + softmax, fp32; NO atomics (counts built in route_finalize via LDS)
__device__ __forceinline__ void topk_write(int* meta, int layer, int t, const float* v) {
  int e0 = 0; float v0 = v[0];
  #pragma unroll
  for (int e = 1; e < 8; ++e) { if (v[e] > v0) { v0 = v[e]; e0 = e; } }
  int e1 = 0; float v1 = -3.4e38f;
  #pragma unroll
  for (int e = 0; e < 8; ++e) { if (e != e0 && v[e] > v1) { v1 = v[e]; e1 = e; } }
  float ex = expf(v1 - v0);
  float p0 = 1.f / (1.f + ex);
  float p1 = ex / (1.f + ex);
  meta[M_TOPKI + (layer * T_NUM + t) * 2    ] = e0;
  meta[M_TOPKI + (layer * T_NUM + t) * 2 + 1] = e1;
  ((float*)meta)[M_TOPKP + (layer * T_NUM + t) * 2    ] = p0;
  ((float*)meta)[M_TOPKP + (layer * T_NUM + t) * 2 + 1] = p1;
}

__global__ __launch_bounds__(256) void router_gu(const float* __restrict__ x,
    const float* __restrict__ Rg, const float* __restrict__ Ru, int* __restrict__ meta)
{
  int w = threadIdx.x >> 6, lane = threadIdx.x & 63;
  int t = blockIdx.x * 4 + w;
  const float* xr = x + (size_t)t * H_DIM + lane * 4;
  f32x4 xv[4];
  #pragma unroll
  for (int c = 0; c < 4; ++c) xv[c] = *(const f32x4*)(xr + c * 256);
  float lg[8], lu[8];
  #pragma unroll
  for (int e = 0; e < 8; ++e) {
    const float* rg = Rg + (size_t)e * H_DIM + lane * 4;
    const float* ru = Ru + (size_t)e * H_DIM + lane * 4;
    float sg = 0.f, su = 0.f;
    #pragma unroll
    for (int c = 0; c < 4; ++c) {
      f32x4 a = *(const f32x4*)(rg + c * 256);
      f32x4 b = *(const f32x4*)(ru + c * 256);
      sg += a[0]*xv[c][0] + a[1]*xv[c][1] + a[2]*xv[c][2] + a[3]*xv[c][3];
      su += b[0]*xv[c][0] + b[1]*xv[c][1] + b[2]*xv[c][2] + b[3]*xv[c][3];
    }
    lg[e] = wave_sum(sg);
    lu[e] = wave_sum(su);
  }
  if (lane == 0) {
    topk_write(meta, 0, t, lg);
    topk_write(meta, 1, t, lu);
  }
}

// Single-workgroup routing finalize (LDS atomics; r8-validated).
__global__ __launch_bounds__(256) void route_finalize(int* __restrict__ meta, int l0, int nl) {
  __shared__ int cnt_s[32];
  __shared__ int off_s[32];
  __shared__ int cur_s[32];
  int tid = threadIdx.x;
  if (tid < 32) { cnt_s[tid] = 0; cur_s[tid] = 0; }
  __syncthreads();
  for (int t = tid; t < T_NUM; t += 256) {
    for (int l = l0; l < l0 + nl; ++l) {
      int li = l - l0;
      #pragma unroll
      for (int k = 0; k < 2; ++k) {
        int e = meta[M_TOPKI + (l * T_NUM + t) * 2 + k];
        atomicAdd(&cnt_s[li * 16 + k * 8 + e], 1);
      }
    }
  }
  __syncthreads();
  if (tid == 0) {
    for (int l = l0; l < l0 + nl; ++l) {
      int li = l - l0;
      int off = 0;
      for (int k = 0; k < 2; ++k) {
        int nt = 0;
        for (int e = 0; e < 8; ++e) {
          int s = (l * 2 + k) * 8 + e;
          int c = cnt_s[li * 16 + k * 8 + e];
          meta[M_COUNTS + s] = c;
          meta[M_OFFSETS + s] = off;
          off_s[li * 16 + k * 8 + e] = off;
          for (int m = 0; m < c; m += 128) {
            meta[M_TILE_E + (l * 2 + k) * MAXTILES + nt] = e;
            meta[M_TILE_M + (l * 2 + k) * MAXTILES + nt] = m;
            ++nt;
          }
          off += c;
        }
        meta[M_NTILES + l * 2 + k] = nt;
      }
    }
  }
  __syncthreads();
  for (int t = tid; t < T_NUM; t += 256) {
    for (int l = l0; l < l0 + nl; ++l) {
      int li = l - l0;
      #pragma unroll
      for (int k = 0; k < 2; ++k) {
        int e = meta[M_TOPKI + (l * T_NUM + t) * 2 + k];
        float p = ((float*)meta)[M_TOPKP + (l * T_NUM + t) * 2 + k];
        int si = li * 16 + k * 8 + e;
        int pos = off_s[si] + atomicAdd(&cur_s[si], 1);
        meta[M_STOK + l * 8192 + pos] = t;
        ((float*)meta)[M_SPRB + l * 8192 + pos] = p;
      }
    }
  }
}

// W pre-convert: fp32 [E][N][K] -> tiled f16 hi/lo planes. (Validated r2-r14.)
template<int SPLITS>
__global__ __launch_bounds__(256) void convert_w(const float* __restrict__ W,
    _Float16* __restrict__ Whi, _Float16* __restrict__ Wlo, int NB, int KT)
{
  size_t g = (size_t)blockIdx.x * 256 + threadIdx.x;
  int c   = (int)(g >> 9);
  int rem = (int)(g & 511);
  int fq = rem >> 7, r = rem & 127;
  int e  = c / (NB * KT);
  int nb = (c / KT) % NB;
  int kt = c - (c / KT) * KT;
  int K = KT * 32, N = NB * 128;
  const float* src = W + ((size_t)(e * N + nb * 128 + r)) * K + kt * 32 + fq * 8;
  f32x4 v0 = *(const f32x4*)src;
  f32x4 v1 = *(const f32x4*)(src + 4);
  f16x8 h, l;
  #pragma unroll
  for (int q = 0; q < 8; ++q) {
    float v = (q < 4) ? v0[q] : v1[q - 4];
    _Float16 hv = (_Float16)v;
    h[q] = hv;
    l[q] = (_Float16)(v - (float)hv);
  }
  size_t dst = (size_t)c * 4096 + (size_t)rem * 8;
  *(f16x8*)(Whi + dst) = h;
  if constexpr (SPLITS == 3) *(f16x8*)(Wlo + dst) = l;
}

// A gather+convert (gate/up): x rows -> tile-contiguous hi/lo image. (r6-r14)
__global__ __launch_bounds__(256) void gather_a(const float* __restrict__ X,
    _Float16* __restrict__ Apass, const int* __restrict__ meta, int layer, int kk)
{
  int pass = layer * 2 + kk;
  int tile = blockIdx.x >> 5;            // grid = MAXTILES*32
  int kt   = blockIdx.x & 31;
  if (tile >= meta[M_NTILES + pass]) return;
  int e    = meta[M_TILE_E + pass * MAXTILES + tile];
  int m0   = meta[M_TILE_M + pass * MAXTILES + tile];
  int sidx = pass * 8 + e;
  int cnt  = meta[M_COUNTS + sidx];
  int seg  = meta[M_OFFSETS + sidx];
  const int* stok = meta + M_STOK + layer * 8192 + seg;
  size_t cb = ((size_t)tile * 32 + kt) * 8192;
  #pragma unroll
  for (int j = 0; j < 2; ++j) {
    int idx = threadIdx.x * 2 + j;       // [0,512): fq = idx>>7, row = idx&127
    int fq = idx >> 7, row = idx & 127;
    int m = m0 + row; if (m >= cnt) m = cnt - 1;
    const float* src = X + (size_t)stok[m] * H_DIM + kt * 32 + fq * 8;
    f32x4 v0 = *(const f32x4*)src;
    f32x4 v1 = *(const f32x4*)(src + 4);
    f16x8 h, l;
    #pragma unroll
    for (int q = 0; q < 8; ++q) {
      float v = (q < 4) ? v0[q] : v1[q - 4];
      _Float16 hv = (_Float16)v;
      h[q] = hv;
      l[q] = (_Float16)(v - (float)hv);
    }
    *(f16x8*)(Apass + cb + (size_t)idx * 8) = h;
    *(f16x8*)(Apass + cb + 4096 + (size_t)idx * 8) = l;
  }
}

// A gather (down): f16 inter rows -> tiled f16 image (pure reorder, no cvt).
__global__ __launch_bounds__(256) void gather_d(const _Float16* __restrict__ Gi,
    _Float16* __restrict__ Ad, const int* __restrict__ meta, int kk)
{
  int pass = 4 + kk;
  int tile = blockIdx.x >> 7;            // grid = MAXTILES*128
  int kt   = blockIdx.x & 127;
  if (tile >= meta[M_NTILES + pass]) return;
  int e    = meta[M_TILE_E + pass * MAXTILES + tile];
  int m0   = meta[M_TILE_M + pass * MAXTILES + tile];
  int sidx = pass * 8 + e;
  int cnt  = meta[M_COUNTS + sidx];
  int seg  = meta[M_OFFSETS + sidx];
  const int* stok = meta + M_STOK + 2 * 8192 + seg;
  size_t cb = ((size_t)tile * 128 + kt) * 4096;
  #pragma unroll
  for (int j = 0; j < 2; ++j) {
    int idx = threadIdx.x * 2 + j;       // [0,512)
    int fq = idx >> 7, row = idx & 127;
    int m = m0 + row; if (m >= cnt) m = cnt - 1;
    f16x8 h = *(const f16x8*)(Gi + (size_t)stok[m] * I_DIM + kt * 32 + fq * 8);
    *(f16x8*)(Ad + cb + (size_t)idx * 8) = h;
  }
}

__device__ __forceinline__ void gload16(const _Float16* g, _Float16* l) {
  __builtin_amdgcn_global_load_lds(
      (const __attribute__((address_space(1))) void*)g,
      (__attribute__((address_space(3))) void*)l, 16, 0, 0);
}

// Routed GEMM v9 (r10-proven, reverted verbatim): 128x128 tile, 4 waves,
// A 3-deep LDS ring via global_load_lds (2 ahead), W reg-dbuf 1 ahead,
// vmcnt(12) + raw barrier, persistent blocks (grid 768, bounds(256,3)).
template<int SPLITS, int ADD, int N, int NB, int STEPS, int SPLITK>
__global__ __launch_bounds__(256, 3) void moe_gemm9(
    const _Float16* __restrict__ Aimg,
    const _Float16* __restrict__ Whi, const _Float16* __restrict__ Wlo,
    float* __restrict__ Out, float* __restrict__ Scr,
    const int* __restrict__ meta, int layer, int kk)
{
  constexpr int NWG = MAXTILES * NB * SPLITK;
  constexpr int Q8  = NWG / 8;
  constexpr int WCH = (SPLITS == 3) ? 1 : 2;

  int xcd  = (int)blockIdx.x & 7;
  int slot = (int)blockIdx.x >> 3;
  int nper = (int)gridDim.x >> 3;
  int pass = layer * 2 + kk;
  int ntiles = meta[M_NTILES + pass];

  __shared__ __align__(16) _Float16 sA[3 * 8192];

  int tid = threadIdx.x, lane = tid & 63, w = tid >> 6;
  int wr = w >> 1, wc = w & 1, fr = lane & 15, fq = lane >> 4;
  int aoff = (fq * 128 + wr * 64 + fr) * 8;

  for (int base = slot; base < Q8; base += nper) {
    int logical = xcd * Q8 + base;
    int kc = 0, rem = logical;
    if constexpr (SPLITK == 2) { kc = logical / (MAXTILES * NB); rem = logical - kc * (MAXTILES * NB); }
    int tx = rem / NB;
    int ny = rem - tx * NB;
    if (tx >= ntiles) continue;

    int e    = meta[M_TILE_E + pass * MAXTILES + tx];
    int m0   = meta[M_TILE_M + pass * MAXTILES + tx];
    int sidx = pass * 8 + e;
    int cnt  = meta[M_COUNTS + sidx];
    int seg  = meta[M_OFFSETS + sidx];
    int n0   = ny * 128;

    const int*   stok = meta + M_STOK + layer * 8192 + seg;
    const float* sprb = (const float*)meta + M_SPRB + layer * 8192 + seg;

    const _Float16* At = Aimg + ((size_t)tx * SPLITK + kc) * STEPS * 8192;
    size_t wpanel = (size_t)(e * NB + ny) * (STEPS * WCH * SPLITK) * 4096;
    int kb = kc * STEPS * WCH;
    const _Float16* WhL = Whi + wpanel + (size_t)kb * 4096 + (fq * 128 + wc * 64 + fr) * 8;
    const _Float16* WlL = Wlo + wpanel + (size_t)kb * 4096 + (fq * 128 + wc * 64 + fr) * 8;

    auto stageA = [&](int it, int slot2) {
      const _Float16* s0 = At + (size_t)it * 8192 + w * 1024 + lane * 8;
      _Float16* d0 = sA + slot2 * 8192 + w * 1024;
      gload16(s0,        d0);
      gload16(s0 + 512,  d0 + 512);
      gload16(s0 + 4096, d0 + 4096);
      gload16(s0 + 4608, d0 + 4608);
    };
    auto loadW = [&](int it, f16x8 (&wh)[WCH][4], f16x8 (&wl)[1][4]) {
      #pragma unroll
      for (int c = 0; c < WCH; ++c) {
        size_t cb = (size_t)(it * WCH + c) * 4096;
        #pragma unroll
        for (int ni = 0; ni < 4; ++ni) wh[c][ni] = *(const f16x8*)(WhL + cb + ni * 128);
      }
      if constexpr (SPLITS == 3) {
        size_t cb = (size_t)it * 4096;
        #pragma unroll
        for (int ni = 0; ni < 4; ++ni) wl[0][ni] = *(const f16x8*)(WlL + cb + ni * 128);
      }
    };

    f32x4 acc[4][4];
    #pragma unroll
    for (int i = 0; i < 4; ++i)
      #pragma unroll
      for (int j = 0; j < 4; ++j) acc[i][j] = f32x4{0.f, 0.f, 0.f, 0.f};

    f16x8 w0h[WCH][4], w0l[1][4], w1h[WCH][4], w1l[1][4];
    int rc = 0, rs = 2;

    auto step = [&](int it, f16x8 (&cwh)[WCH][4], f16x8 (&cwl)[1][4],
                    f16x8 (&nwh)[WCH][4], f16x8 (&nwl)[1][4]) {
      int it2 = (it + 2 < STEPS) ? it + 2 : STEPS - 1;
      int it1 = (it + 1 < STEPS) ? it + 1 : STEPS - 1;
      stageA(it2, rs);
      loadW(it1, nwh, nwl);
      __builtin_amdgcn_sched_barrier(0);

      const _Float16* A0 = sA + rc * 8192;
      __builtin_amdgcn_s_setprio(1);
      if constexpr (SPLITS == 3) {
        f16x8 ah[4], al[4];
        #pragma unroll
        for (int mi = 0; mi < 4; ++mi) ah[mi] = *(const f16x8*)(A0 + aoff + mi * 128);
        #pragma unroll
        for (int mi = 0; mi < 4; ++mi) al[mi] = *(const f16x8*)(A0 + 4096 + aoff + mi * 128);
        #pragma unroll
        for (int mi = 0; mi < 4; ++mi)
          #pragma unroll
          for (int ni = 0; ni < 4; ++ni)
            acc[mi][ni] = __builtin_amdgcn_mfma_f32_16x16x32_f16(ah[mi], cwh[0][ni], acc[mi][ni], 0, 0, 0);
        #pragma unroll
        for (int mi = 0; mi < 4; ++mi)
          #pragma unroll
          for (int ni = 0; ni < 4; ++ni)
            acc[mi][ni] = __builtin_amdgcn_mfma_f32_16x16x32_f16(ah[mi], cwl[0][ni], acc[mi][ni], 0, 0, 0);
        #pragma unroll
        for (int mi = 0; mi < 4; ++mi)
          #pragma unroll
          for (int ni = 0; ni < 4; ++ni)
            acc[mi][ni] = __builtin_amdgcn_mfma_f32_16x16x32_f16(al[mi], cwh[0][ni], acc[mi][ni], 0, 0, 0);
      } else {
        #pragma unroll
        for (int c = 0; c < WCH; ++c) {
          f16x8 ah[4];
          #pragma unroll
          for (int mi = 0; mi < 4; ++mi) ah[mi] = *(const f16x8*)(A0 + c * 4096 + aoff + mi * 128);
          #pragma unroll
          for (int mi = 0; mi < 4; ++mi)
            #pragma unroll
            for (int ni = 0; ni < 4; ++ni)
              acc[mi][ni] = __builtin_amdgcn_mfma_f32_16x16x32_f16(ah[mi], cwh[c][ni], acc[mi][ni], 0, 0, 0);
        }
      }
      __builtin_amdgcn_s_setprio(0);

      __builtin_amdgcn_sched_barrier(0);
      asm volatile("s_waitcnt vmcnt(12)" ::: "memory");
      __builtin_amdgcn_s_barrier();
      __builtin_amdgcn_sched_barrier(0);
      rc = (rc == 2) ? 0 : rc + 1;
      rs = (rs == 2) ? 0 : rs + 1;
    };

    // assignment prologue (drain wrapped DMA from previous assignment first)
    asm volatile("s_waitcnt vmcnt(0)" ::: "memory");
    __builtin_amdgcn_s_barrier();
    stageA(0, 0);
    stageA(1 < STEPS ? 1 : 0, 1);
    loadW(0, w0h, w0l);
    __builtin_amdgcn_sched_barrier(0);
    asm volatile("s_waitcnt vmcnt(12)" ::: "memory");
    __builtin_amdgcn_s_barrier();
    __builtin_amdgcn_sched_barrier(0);

    for (int it = 0; it < STEPS; it += 2) {
      step(it,     w0h, w0l, w1h, w1l);
      step(it + 1, w1h, w1l, w0h, w0l);
    }

    float* dst = (SPLITK == 2 && kc == 1) ? Scr : Out;
    #pragma unroll
    for (int mi = 0; mi < 4; ++mi) {
      #pragma unroll
      for (int jj = 0; jj < 4; ++jj) {
        int lm = wr * 64 + mi * 16 + fq * 4 + jj;
        int gm = m0 + lm;
        if (gm < cnt) {
          int tok = stok[gm];
          float p = sprb[gm];
          float* orow = dst + (size_t)tok * N + n0 + wc * 64 + fr;
          #pragma unroll
          for (int ni = 0; ni < 4; ++ni) {
            float v = p * acc[mi][ni][jj];
            if constexpr (ADD) orow[ni * 16] += v; else orow[ni * 16] = v;
          }
        }
      }
    }
  }
}

// fused SwiGLU + down-router; writes inter as f16 (same rounding gather_d
// applied before), logits from fp32 registers (routing decisions unchanged).
__global__ __launch_bounds__(256) void swiglu_router(const float* __restrict__ g,
    const float* __restrict__ u, const float* __restrict__ Rd,
    _Float16* __restrict__ gi, int* __restrict__ meta)
{
  int t = blockIdx.x, tid = threadIdx.x;
  float part[8];
  #pragma unroll
  for (int e = 0; e < 8; ++e) part[e] = 0.f;
  const float* gr = g + (size_t)t * I_DIM;
  const float* ur = u + (size_t)t * I_DIM;
  _Float16*    ir = gi + (size_t)t * I_DIM;
  #pragma unroll
  for (int cc = 0; cc < 4; ++cc) {
    int i = cc * 1024 + tid * 4;
    f32x4 gv = *(const f32x4*)(gr + i);
    f32x4 uv = *(const f32x4*)(ur + i);
    f32x4 iv;
    f16x4 hv;
    #pragma unroll
    for (int j = 0; j < 4; ++j) {
      float xx = gv[j];
      iv[j] = (xx / (1.f + expf(-xx))) * uv[j];
      hv[j] = (_Float16)iv[j];
    }
    *(f16x4*)(ir + i) = hv;
    #pragma unroll
    for (int e = 0; e < 8; ++e) {
      f32x4 rv = *(const f32x4*)(Rd + (size_t)e * I_DIM + i);
      part[e] += rv[0]*iv[0] + rv[1]*iv[1] + rv[2]*iv[2] + rv[3]*iv[3];
    }
  }
  __shared__ float red[4][8];
  int w = tid >> 6, lane = tid & 63;
  #pragma unroll
  for (int e = 0; e < 8; ++e) {
    float s = wave_sum(part[e]);
    if (lane == 0) red[w][e] = s;
  }
  __syncthreads();
  if (tid == 0) {
    float lg[8];
    #pragma unroll
    for (int e = 0; e < 8; ++e) lg[e] = red[0][e] + red[1][e] + red[2][e] + red[3][e];
    topk_write(meta, 2, t, lg);
  }
}

__global__ __launch_bounds__(256) void combine_kernel(float* __restrict__ out,
                                                      const float* __restrict__ scr)
{
  int i = blockIdx.x * 1024 + threadIdx.x * 4;
  f32x4 a = *(const f32x4*)(out + i);
  f32x4 b = *(const f32x4*)(scr + i);
  #pragma unroll
  for (int j = 0; j < 4; ++j) a[j] += b[j];
  *(f32x4*)(out + i) = a;
}

extern "C" void kernel_launch(void* const* d_in, const int* in_sizes, int n_in,
                              void* d_out, int out_size, void* d_ws, size_t ws_size,
                              hipStream_t stream)
{
  const float* x  = (const float*)d_in[0];
  const float* Rg = (const float*)d_in[1];
  const float* Wg = (const float*)d_in[2];
  const float* Ru = (const float*)d_in[3];
  const float* Wu = (const float*)d_in[4];
  const float* Rd = (const float*)d_in[5];
  const float* Wd = (const float*)d_in[6];
  float* out = (float*)d_out;
  char* ws = (char*)d_ws;

  _Float16* Wth = (_Float16*)ws;                          // 67MB tiled hi plane
  _Float16* Wtl = (_Float16*)(ws + (size_t)67108864);     // 67MB tiled lo plane (dead after up-GEMMs)
  float* g   = (float*)(ws + (size_t)134217728);          // [T, I] fp32 (gate raw)
  float* u   = (float*)(ws + (size_t)201326592);          // [T, I] fp32; dead after swiglu
  int*  meta = (int*)(ws + (size_t)268435456);            // ~0.4MB
  _Float16* Apass = (_Float16*)(ws + (size_t)269484032);  // 21MB gate/up A image
  _Float16* gi    = (_Float16*)Wtl;                       // [T, I] f16 inter (33.5MB, in dead Wtl)
  _Float16* Ad    = (_Float16*)(ws + (size_t)201326592);  // down A image (in dead u)
  float* dscr     = (float*)(ws + (size_t)269484032);     // down splitK scratch (in dead Apass)

  router_gu<<<dim3(T_NUM / 4), 256, 0, stream>>>(x, Rg, Ru, meta);
  route_finalize<<<dim3(1), 256, 0, stream>>>(meta, 0, 2);

  convert_w<3><<<dim3(16384), 256, 0, stream>>>(Wg, Wth, Wtl, 32, 32);
  gather_a<<<dim3(MAXTILES * 32), 256, 0, stream>>>(x, Apass, meta, 0, 0);
  moe_gemm9<3, 0, I_DIM, 32, 32, 1><<<dim3(768), 256, 0, stream>>>(
      Apass, Wth, Wtl, g, g, meta, 0, 0);
  gather_a<<<dim3(MAXTILES * 32), 256, 0, stream>>>(x, Apass, meta, 0, 1);
  moe_gemm9<3, 1, I_DIM, 32, 32, 1><<<dim3(768), 256, 0, stream>>>(
      Apass, Wth, Wtl, g, g, meta, 0, 1);

  convert_w<3><<<dim3(16384), 256, 0, stream>>>(Wu, Wth, Wtl, 32, 32);
  gather_a<<<dim3(MAXTILES * 32), 256, 0, stream>>>(x, Apass, meta, 1, 0);
  moe_gemm9<3, 0, I_DIM, 32, 32, 1><<<dim3(768), 256, 0, stream>>>(
      Apass, Wth, Wtl, u, u, meta, 1, 0);
  gather_a<<<dim3(MAXTILES * 32), 256, 0, stream>>>(x, Apass, meta, 1, 1);
  moe_gemm9<3, 1, I_DIM, 32, 32, 1><<<dim3(768), 256, 0, stream>>>(
      Apass, Wth, Wtl, u, u, meta, 1, 1);

  // Wtl dead from here; gi (f16 inter) lives in it
  swiglu_router<<<dim3(T_NUM), 256, 0, stream>>>(g, u, Rd, gi, meta);
  route_finalize<<<dim3(1), 256, 0, stream>>>(meta, 2, 1);

  convert_w<1><<<dim3(16384), 256, 0, stream>>>(Wd, Wth, Wth, 8, 128);
  gather_d<<<dim3(MAXTILES * 128), 256, 0, stream>>>(gi, Ad, meta, 0);
  moe_gemm9<1, 0, H_DIM, 8, 32, 2><<<dim3(768), 256, 0, stream>>>(
      Ad, Wth, Wth, out, dscr, meta, 2, 0);
  gather_d<<<dim3(MAXTILES * 128), 256, 0, stream>>>(gi, Ad, meta, 1);
  moe_gemm9<1, 1, H_DIM, 8, 32, 2><<<dim3(768), 256, 0, stream>>>(
      Ad, Wth, Wth, out, dscr, meta, 2, 1);
  combine_kernel<<<dim3(T_NUM), 256, 0, stream>>>(out, dscr);
}